// Round 9
// baseline (147.710 us; speedup 1.0000x reference)
//
#include <hip/hip_runtime.h>
#include <cmath>

typedef float floatx4 __attribute__((ext_vector_type(4)));
typedef __bf16 bf16x8 __attribute__((ext_vector_type(8)));
typedef unsigned uintx4 __attribute__((ext_vector_type(4)));

#define NDT 512
#define NELF 262144.0f

// ---- ws layout (float idx) ----
// FLAG    uint [0..2048)    at (rg*8+cb)*8 — AGENT scope (rg round TRUTH flag,
//                            XCC exchange at +4). Proven transport (R2/R6/R8).
// FLAG_RG uint [2048..4096) at (rg*8+cb)*8 — L2-scope HINT copy of the rg flag
//                            (plain store / sc0+nt poll). Accelerator only:
//                            the waiter polls the agent truth flag in the SAME
//                            loop iteration, so a dead hint cannot hang and
//                            costs ~nothing. nt avoids L1 allocation (the
//                            suspected stale-poll hazard of R1/R3).
// PART1 float [4096..10240) at sa*256 + blk — grid-reduce partials, agent
//                            scope, data-as-flag (proven R6/R8).
// AF0 16384, AF1 16384+262144 (basis parity buffers, bf16 1 MiB each)
// YF reuses AF0 region after the final grid-wide reduce.
#define AF0_OFF 16384
#define AF1_OFF (16384 + 262144)
#define BFC_OFF (16384 + 2 * 262144)
#define BFP_OFF (BFC_OFF + 262144)
#define BFF_OFF (BFP_OFF + 131072)

#define RTOLc 1e-3f
#define ATOLc 1e-6f
#define TAc 1.0f
#define TBc 1.0f
#define TCc 0.0f

union UB { uint4 u; bf16x8 v; };
union UB2 { unsigned long long q[2]; uint4 u; bf16x8 v; uintx4 x; };

__device__ __forceinline__ uint32_t f2bf(float f) {
  uint32_t u = __float_as_uint(f);
  return (u + 0x7fffu + ((u >> 16) & 1u)) >> 16;
}

#define AST(p, v) __hip_atomic_store((p), (v), __ATOMIC_RELAXED, __HIP_MEMORY_SCOPE_AGENT)
#define ALD(p) __hip_atomic_load((p), __ATOMIC_RELAXED, __HIP_MEMORY_SCOPE_AGENT)

// L1-bypass load (sc0): serves from the XCD's L2. Data path proven (R2/R6/R8).
__device__ __forceinline__ uintx4 ld128_x(const void* p) {
  uintx4 r;
  asm volatile("global_load_dwordx4 %0, %1, off sc0\n\ts_waitcnt vmcnt(0)"
               : "=v"(r) : "v"(p) : "memory");
  return r;
}

// ---- pack: C (coalesced-read/scatter-write, proven) + P/F gather-style; zero ctl ----
__global__ __launch_bounds__(256) void pack_all(const float* __restrict__ C,
                                                const float* __restrict__ P,
                                                const float* __restrict__ F,
                                                __bf16* __restrict__ BfC,
                                                unsigned* __restrict__ BfP,
                                                unsigned* __restrict__ BfF,
                                                unsigned* __restrict__ ctl) {
  const int bid = blockIdx.x, tid = threadIdx.x;
  if (bid == 0) {
    for (int i = tid; i < 10240; i += 256) ctl[i] = 0u;  // FLAG + FLAG_RG + PART1
  }
  if (bid < 512) {
    int t = bid * 256 + tid;
    int i = t >> 8;
    int pr = t & 255;  // K0 = pr*4
    floatx4 v = *(const floatx4*)(C + (size_t)i * 1024 + pr * 4);
    uint32_t w0 = f2bf(v[0]) | (f2bf(v[1]) << 16);
    uint32_t w1 = f2bf(v[2]) | (f2bf(v[3]) << 16);
    int c0 = i >> 4;
    int kc = pr >> 3;
    int lq = (pr >> 1) & 3;
    int ln = (i & 15) | (lq << 4);
    int jp = (pr & 1) * 4;
    uint2 val; val.x = w0; val.y = w1;
    *(uint2*)(BfC + ((size_t)(c0 * 32 + kc) * 64 + ln) * 8 + jp) = val;
  } else {
    // gather-style: one thread builds one 16-B frag line (8 bf16 along K)
    const float* M = (bid < 640) ? P : F;
    unsigned* Bf = (bid < 640) ? BfP : BfF;
    int t = ((bid < 640) ? (bid - 512) : (bid - 640)) * 256 + tid;  // 0..32767
    int lane = t & 63;
    int kc = (t >> 6) & 15;
    int nf = t >> 10;
    int n = nf * 16 + (lane & 15);
    int K0 = kc * 32 + ((lane >> 4) & 3) * 8;
    const float* mp = M + (size_t)K0 * NDT + n;
    uint32_t e0 = f2bf(mp[0]);
    uint32_t e1 = f2bf(mp[512]);
    uint32_t e2 = f2bf(mp[1024]);
    uint32_t e3 = f2bf(mp[1536]);
    uint32_t e4 = f2bf(mp[2048]);
    uint32_t e5 = f2bf(mp[2560]);
    uint32_t e6 = f2bf(mp[3072]);
    uint32_t e7 = f2bf(mp[3584]);
    *(uint4*)(Bf + ((size_t)(nf * 16 + kc) * 64 + lane) * 4) =
        make_uint4(e0 | (e1 << 16), e2 | (e3 << 16), e4 | (e5 << 16), e6 | (e7 << 16));
  }
}

// ---- fused kernel: A0 GEMM + RK45 + out GEMM; plain launch, co-residency by
// capacity (grid=256=CU count, launch_bounds(256,1), ~52 KB LDS). ----
__global__ __launch_bounds__(256, 1) void ode_mfma(const float* __restrict__ x,
                                                   float* __restrict__ out,
                                                   float* __restrict__ ws) {
  // double-buffered cross-wave reduction scratch (R8): parity alternates per
  // call, making the leading __syncthreads of the classic reduce redundant.
  __shared__ __align__(16) float red[2][4][16][68];
  __shared__ __align__(16) unsigned short ldsX[16 * 64 * 8];  // 16 KiB
  __shared__ float bred[4];
  __shared__ float shb0s, shb1s;
  __shared__ unsigned sxc[8];

  unsigned* FLAG = (unsigned*)ws;               // agent truth flags (+XCC at +4)
  unsigned* FLAG_RG = (unsigned*)ws + 2048;     // L2-scope hint flags
  float* PART1 = ws + 4096;                     // sa*256 + blk (data-as-flag)
  unsigned long long* AfA = (unsigned long long*)(ws + AF0_OFF);
  unsigned long long* AfB = (unsigned long long*)(ws + AF1_OFF);
  unsigned long long* YF = (unsigned long long*)(ws + AF0_OFF);  // reused post-loop
  const __bf16* Bf = (const __bf16*)(ws + BFC_OFF);
  const __bf16* BfP = (const __bf16*)(ws + BFP_OFF);
  const __bf16* BfF = (const __bf16*)(ws + BFF_OFF);

  const int tid = threadIdx.x;
  const int lane = tid & 63;
  const int w = tid >> 6;          // wave id = K-chunk
  const int cb = blockIdx.x >> 5;  // col-slice 64*cb..64*cb+63
  const int rg = blockIdx.x & 31;  // rows 16*rg..16*rg+15
  const int rl = tid & 15;         // owned row
  const int gcq = cb * 16 + (tid >> 4);  // owned global col-quad
  const int blk = rg * 8 + cb;     // flag slot id

  // ---- one-round XCC_ID exchange through the proven agent flag array ----
  bool fastp;
  {
    unsigned myxcc;
    asm volatile("s_getreg_b32 %0, hwreg(HW_REG_XCC_ID)" : "=s"(myxcc));
    myxcc &= 15u;
    if (tid == 0) AST(&FLAG[blk * 8 + 4], myxcc + 1u);
    if (tid < 8) {
      unsigned v;
      while ((v = ALD(&FLAG[(rg * 8 + tid) * 8 + 4])) == 0u) __builtin_amdgcn_s_sleep(1);
      sxc[tid] = v;
    }
    __syncthreads();
    fastp = true;
#pragma unroll
    for (int i = 0; i < 8; ++i) fastp = fastp && (sxc[i] == sxc[0]);
  }

  // persistent register-resident C-frags (K=1024): wave w owns kc 8w..8w+7
  UB Breg[4][8];
#pragma unroll
  for (int cf = 0; cf < 4; ++cf)
#pragma unroll
    for (int i = 0; i < 8; ++i)
      Breg[cf][i].u =
          *(const uint4*)(Bf + (((size_t)(cb * 4 + cf) * 32 + 8 * w + i) * 64 + lane) * 8);

  int rg_phase = 0, par = 0, r4p = 0;

  // arrive: post L2 hint (plain store -> shared XCD L2) + agent truth flag.
  // wait: 8 lanes each poll hint (sc0 nt: no L1 allocate) AND truth (agent)
  // in one iteration, exiting on whichever shows first. Hint-exit is sound:
  // producer's basis stores drained to the same L2 before its hint store.
  // Liveness never depends on the hint — worst case == proven R8 cadence.
  auto rg_barrier = [&]() {
    __syncthreads();  // compiler emits s_waitcnt vmcnt(0) before s_barrier
    ++rg_phase;
    if (tid == 0) {
      if (fastp) *(volatile unsigned*)&FLAG_RG[blk * 8] = (unsigned)rg_phase;
      AST(&FLAG[blk * 8], (unsigned)rg_phase);
    }
    if (tid < 8) {
      if (fastp) {
        const unsigned* hp = &FLAG_RG[(rg * 8 + tid) * 8];
        const unsigned* gp = &FLAG[(rg * 8 + tid) * 8];
        while (true) {
          unsigned a, b;
          asm volatile(
              "global_load_dword %0, %2, off sc0 nt\n\t"
              "global_load_dword %1, %3, off sc0 sc1\n\t"
              "s_waitcnt vmcnt(0)"
              : "=&v"(a), "=&v"(b) : "v"(hp), "v"(gp) : "memory");
          if (a >= (unsigned)rg_phase || b >= (unsigned)rg_phase) break;
        }
      } else {
        while (ALD(&FLAG[(rg * 8 + tid) * 8]) < (unsigned)rg_phase)
          __builtin_amdgcn_s_sleep(1);
      }
    }
    __syncthreads();
  };

  // cross-wave K-reduction (parity double-buffered, single barrier — R8)
  auto reduce4 = [&](floatx4 a0, floatx4 a1, floatx4 a2, floatx4 a3) -> floatx4 {
    const int p = r4p;
    r4p ^= 1;
    const int q = lane >> 4, l4 = lane & 15;
#pragma unroll
    for (int ri = 0; ri < 4; ++ri) {
      red[p][w][4 * q + ri][l4] = a0[ri];
      red[p][w][4 * q + ri][16 + l4] = a1[ri];
      red[p][w][4 * q + ri][32 + l4] = a2[ri];
      red[p][w][4 * q + ri][48 + l4] = a3[ri];
    }
    __syncthreads();
    const int c0 = (tid >> 4) * 4;
    floatx4 o = *(const floatx4*)&red[p][0][rl][c0];
    o += *(const floatx4*)&red[p][1][rl][c0];
    o += *(const floatx4*)&red[p][2][rl][c0];
    o += *(const floatx4*)&red[p][3][rl][c0];
    return o;
  };

  // basis write slot (K=1024 frag layout, sin/cos interleaved over K=2*col)
  const int kcw = gcq >> 2;
  const int alw = rl | ((gcq & 3) << 4);
  const size_t wslot = ((size_t)(rg * 32 + kcw) * 64 + alw) * 2;

  auto write_basis = [&](floatx4 av_, float targ) {
    uint32_t d[4];
#pragma unroll
    for (int e = 0; e < 4; ++e) {
      float s, c;
      __sincosf(TAc * av_[e] + targ, &s, &c);
      d[e] = f2bf(s) | (f2bf(c) << 16);
    }
    unsigned long long* Ap = (par ? AfB : AfA) + wslot;
    if (fastp) {
      uintx4 u = {d[0], d[1], d[2], d[3]};
      *(volatile uintx4*)Ap = u;  // plain write-through store -> XCD L2
    } else {
      AST(Ap, (unsigned long long)d[0] | ((unsigned long long)d[1] << 32));
      AST(Ap + 1, (unsigned long long)d[2] | ((unsigned long long)d[3] << 32));
    }
  };

  auto gemm = [&]() -> floatx4 {
    const unsigned long long* Ap =
        (par ? AfB : AfA) + ((size_t)(rg * 32 + 8 * w) * 64 + lane) * 2;
    UB2 a[8];
    floatx4 acc0 = {0.f, 0.f, 0.f, 0.f}, acc1 = acc0, acc2 = acc0, acc3 = acc0;
    if (fastp) {
      // 8 batched 16B sc0 loads; split waitcnt: vmcnt(4) releases frags 0-3
      // (MFMA overlaps in-flight frags 4-7), vmcnt(0) + sched_barrier(0)
      // fences the rest (rule #18). Proven R8.
      const char* b0 = (const char*)Ap;
      const char* b1 = b0 + 4096;
      uintx4 t0, t1, t2, t3, t4, t5, t6, t7;
      asm volatile(
          "global_load_dwordx4 %0, %4, off sc0\n\t"
          "global_load_dwordx4 %1, %4, off offset:1024 sc0\n\t"
          "global_load_dwordx4 %2, %4, off offset:2048 sc0\n\t"
          "global_load_dwordx4 %3, %4, off offset:3072 sc0"
          : "=&v"(t0), "=&v"(t1), "=&v"(t2), "=&v"(t3)
          : "v"(b0)
          : "memory");
      asm volatile(
          "global_load_dwordx4 %0, %4, off sc0\n\t"
          "global_load_dwordx4 %1, %4, off offset:1024 sc0\n\t"
          "global_load_dwordx4 %2, %4, off offset:2048 sc0\n\t"
          "global_load_dwordx4 %3, %4, off offset:3072 sc0\n\t"
          "s_waitcnt vmcnt(4)"
          : "=&v"(t4), "=&v"(t5), "=&v"(t6), "=&v"(t7)
          : "v"(b1)
          : "memory");
      __builtin_amdgcn_sched_barrier(0);
      a[0].x = t0; a[1].x = t1; a[2].x = t2; a[3].x = t3;
#pragma unroll
      for (int i = 0; i < 4; ++i) {
        acc0 = __builtin_amdgcn_mfma_f32_16x16x32_bf16(a[i].v, Breg[0][i].v, acc0, 0, 0, 0);
        acc1 = __builtin_amdgcn_mfma_f32_16x16x32_bf16(a[i].v, Breg[1][i].v, acc1, 0, 0, 0);
        acc2 = __builtin_amdgcn_mfma_f32_16x16x32_bf16(a[i].v, Breg[2][i].v, acc2, 0, 0, 0);
        acc3 = __builtin_amdgcn_mfma_f32_16x16x32_bf16(a[i].v, Breg[3][i].v, acc3, 0, 0, 0);
      }
      asm volatile("s_waitcnt vmcnt(0)" ::: "memory");
      __builtin_amdgcn_sched_barrier(0);
      a[4].x = t4; a[5].x = t5; a[6].x = t6; a[7].x = t7;
#pragma unroll
      for (int i = 4; i < 8; ++i) {
        acc0 = __builtin_amdgcn_mfma_f32_16x16x32_bf16(a[i].v, Breg[0][i].v, acc0, 0, 0, 0);
        acc1 = __builtin_amdgcn_mfma_f32_16x16x32_bf16(a[i].v, Breg[1][i].v, acc1, 0, 0, 0);
        acc2 = __builtin_amdgcn_mfma_f32_16x16x32_bf16(a[i].v, Breg[2][i].v, acc2, 0, 0, 0);
        acc3 = __builtin_amdgcn_mfma_f32_16x16x32_bf16(a[i].v, Breg[3][i].v, acc3, 0, 0, 0);
      }
    } else {
#pragma unroll
      for (int i = 0; i < 8; ++i) {
        a[i].q[0] = ALD(Ap + (size_t)i * 128);
        a[i].q[1] = ALD(Ap + (size_t)i * 128 + 1);
      }
#pragma unroll
      for (int i = 0; i < 8; ++i) {
        acc0 = __builtin_amdgcn_mfma_f32_16x16x32_bf16(a[i].v, Breg[0][i].v, acc0, 0, 0, 0);
        acc1 = __builtin_amdgcn_mfma_f32_16x16x32_bf16(a[i].v, Breg[1][i].v, acc1, 0, 0, 0);
        acc2 = __builtin_amdgcn_mfma_f32_16x16x32_bf16(a[i].v, Breg[2][i].v, acc2, 0, 0, 0);
        acc3 = __builtin_amdgcn_mfma_f32_16x16x32_bf16(a[i].v, Breg[3][i].v, acc3, 0, 0, 0);
      }
    }
    par ^= 1;
    return reduce4(acc0, acc1, acc2, acc3);
  };

  auto block_sum = [&](float v) -> float {
#pragma unroll
    for (int o = 32; o; o >>= 1) v += __shfl_down(v, o, 64);
    __syncthreads();
    if (lane == 0) bred[w] = v;
    __syncthreads();
    return (tid == 0) ? (bred[0] + bred[1] + bred[2] + bred[3]) : 0.0f;
  };

  // single-level deterministic grid reduce (agent scope; data-as-flag, R6/R8)
  auto grid_reduce = [&](float va, float vb, int sa, int sb, bool two) -> float2 {
    float ba = block_sum(va);
    float bb = two ? block_sum(vb) : 0.0f;
    if (tid == 0) {
      AST((unsigned*)&PART1[sa * 256 + blk], __float_as_uint(ba) | 1u);
      if (two) AST((unsigned*)&PART1[sb * 256 + blk], __float_as_uint(bb) | 1u);
    }
    if (w == 0) {
      unsigned ua[4], ub[4];
#pragma unroll
      for (int k = 0; k < 4; ++k) {
        const unsigned* pa = (const unsigned*)&PART1[sa * 256 + lane + 64 * k];
        unsigned v;
        while ((v = ALD(pa)) == 0u) __builtin_amdgcn_s_sleep(1);
        ua[k] = v;
      }
      if (two) {
#pragma unroll
        for (int k = 0; k < 4; ++k) {
          const unsigned* pb = (const unsigned*)&PART1[sb * 256 + lane + 64 * k];
          unsigned v;
          while ((v = ALD(pb)) == 0u) __builtin_amdgcn_s_sleep(1);
          ub[k] = v;
        }
      }
      float x0 = __uint_as_float(ua[0]) + __uint_as_float(ua[1]) +
                 __uint_as_float(ua[2]) + __uint_as_float(ua[3]);
      float x1 = 0.0f;
      if (two)
        x1 = __uint_as_float(ub[0]) + __uint_as_float(ub[1]) +
             __uint_as_float(ub[2]) + __uint_as_float(ub[3]);
#pragma unroll
      for (int o = 32; o; o >>= 1) {
        x0 += __shfl_down(x0, o, 64);
        x1 += __shfl_down(x1, o, 64);
      }
      if (lane == 0) { shb0s = x0; shb1s = x1; }
    }
    __syncthreads();
    return make_float2(shb0s, shb1s);
  };

  // ---- phase A0: y = (x @ P) patch, K=512 MFMA vs pre-packed P-frags ----
  floatx4 y, fy, k2, k3, k4, k5, k6, k7, yn, av;
  {
    for (int idx = tid; idx < 8192; idx += 256) {
      int r = idx >> 9, k = idx & 511;
      float v = x[(size_t)(rg * 16 + r) * NDT + k];
      int al = r | (((k >> 3) & 3) << 4);
      ldsX[((size_t)(k >> 5) * 64 + al) * 8 + (k & 7)] = (unsigned short)f2bf(v);
    }
    __syncthreads();
    floatx4 a0 = {0.f, 0.f, 0.f, 0.f}, a1 = a0, a2 = a0, a3 = a0;
#pragma unroll
    for (int i = 0; i < 4; ++i) {
      UB a, b;
      a.u = *(const uint4*)(ldsX + ((size_t)(4 * w + i) * 64 + lane) * 8);
      b.u = *(const uint4*)(BfP + (((size_t)(cb * 4 + 0) * 16 + 4 * w + i) * 64 + lane) * 8);
      a0 = __builtin_amdgcn_mfma_f32_16x16x32_bf16(a.v, b.v, a0, 0, 0, 0);
      b.u = *(const uint4*)(BfP + (((size_t)(cb * 4 + 1) * 16 + 4 * w + i) * 64 + lane) * 8);
      a1 = __builtin_amdgcn_mfma_f32_16x16x32_bf16(a.v, b.v, a1, 0, 0, 0);
      b.u = *(const uint4*)(BfP + (((size_t)(cb * 4 + 2) * 16 + 4 * w + i) * 64 + lane) * 8);
      a2 = __builtin_amdgcn_mfma_f32_16x16x32_bf16(a.v, b.v, a2, 0, 0, 0);
      b.u = *(const uint4*)(BfP + (((size_t)(cb * 4 + 3) * 16 + 4 * w + i) * 64 + lane) * 8);
      a3 = __builtin_amdgcn_mfma_f32_16x16x32_bf16(a.v, b.v, a3, 0, 0, 0);
    }
    y = reduce4(a0, a1, a2, a3);
  }

  // ---- initial step selection (scipy _select_initial_step) ----
  write_basis(y, TCc + TBc * 0.0f);
  rg_barrier();
  fy = gemm();  // f0
  {
    float s0 = 0.f, s1 = 0.f;
#pragma unroll
    for (int r = 0; r < 4; ++r) {
      float sv = ATOLc + RTOLc * fabsf(y[r]);
      float a = y[r] / sv, b = fy[r] / sv;
      s0 += a * a;
      s1 += b * b;
    }
    float2 d01 = grid_reduce(s0, s1, 0, 1, true);
    const float d0 = sqrtf(d01.x / NELF);
    const float d1 = sqrtf(d01.y / NELF);
    const float h0 = (d0 < 1e-5f || d1 < 1e-5f) ? 1e-6f : 0.01f * d0 / d1;
    av = y + h0 * fy;
    write_basis(av, TCc + TBc * h0);
    rg_barrier();
    k2 = gemm();  // f1 (temp)
    float s2 = 0.f;
#pragma unroll
    for (int r = 0; r < 4; ++r) {
      float sv = ATOLc + RTOLc * fabsf(y[r]);
      float dd = (k2[r] - fy[r]) / sv;
      s2 += dd * dd;
    }
    const float d2 = sqrtf(grid_reduce(s2, 0.f, 2, 0, false).x / NELF) / h0;
    const float dmax = fmaxf(d1, d2);
    const float h1i = (dmax <= 1e-15f) ? fmaxf(1e-6f, h0 * 1e-3f) : powf(0.01f / dmax, 0.2f);
    float h = fminf(fminf(100.0f * h0, h1i), 1.0f);
    float t = 0.0f;
    bool done = false;
    int it = 0;

    const float a21 = (float)(1.0 / 5.0);
    const float a31 = (float)(3.0 / 40.0), a32 = (float)(9.0 / 40.0);
    const float a41 = (float)(44.0 / 45.0), a42 = (float)(-56.0 / 15.0), a43 = (float)(32.0 / 9.0);
    const float a51 = (float)(19372.0 / 6561.0), a52 = (float)(-25360.0 / 2187.0),
                a53 = (float)(64448.0 / 6561.0), a54 = (float)(-212.0 / 729.0);
    const float a61 = (float)(9017.0 / 3168.0), a62 = (float)(-355.0 / 33.0),
                a63 = (float)(46732.0 / 5247.0), a64 = (float)(49.0 / 176.0),
                a65 = (float)(-5103.0 / 18656.0);
    const float b1 = (float)(35.0 / 384.0), b3 = (float)(500.0 / 1113.0),
                b4 = (float)(125.0 / 192.0), b5 = (float)(-2187.0 / 6784.0),
                b6 = (float)(11.0 / 84.0);
    const float e1c = (float)(71.0 / 57600.0), e3c = (float)(-71.0 / 16695.0),
                e4c = (float)(71.0 / 1920.0), e5c = (float)(-17253.0 / 339200.0),
                e6c = (float)(22.0 / 525.0), e7c = (float)(-1.0 / 40.0);
    const float c89 = (float)(8.0 / 9.0);

    while (true) {
      const float hs = fminf(h, 1.0f - t);

      av = y + (hs * a21) * fy;
      write_basis(av, TCc + TBc * (t + 0.2f * hs));
      rg_barrier();
      k2 = gemm();

      av = y + hs * (a31 * fy + a32 * k2);
      write_basis(av, TCc + TBc * (t + 0.3f * hs));
      rg_barrier();
      k3 = gemm();

      av = y + hs * (a41 * fy + a42 * k2 + a43 * k3);
      write_basis(av, TCc + TBc * (t + 0.8f * hs));
      rg_barrier();
      k4 = gemm();

      av = y + hs * (a51 * fy + a52 * k2 + a53 * k3 + a54 * k4);
      write_basis(av, TCc + TBc * (t + c89 * hs));
      rg_barrier();
      k5 = gemm();

      av = y + hs * (a61 * fy + a62 * k2 + a63 * k3 + a64 * k4 + a65 * k5);
      write_basis(av, TCc + TBc * (t + hs));
      rg_barrier();
      k6 = gemm();

      yn = y + hs * (b1 * fy + b3 * k3 + b4 * k4 + b5 * k5 + b6 * k6);
      write_basis(yn, TCc + TBc * (t + hs));  // FSAL stage input
      rg_barrier();
      k7 = gemm();

      float es = 0.f;
#pragma unroll
      for (int r = 0; r < 4; ++r) {
        float errc = hs * (e1c * fy[r] + e3c * k3[r] + e4c * k4[r] + e5c * k5[r] +
                           e6c * k6[r] + e7c * k7[r]);
        float sv = ATOLc + RTOLc * fmaxf(fabsf(y[r]), fabsf(yn[r]));
        float dd = errc / sv;
        es += dd * dd;
      }
      const float en = sqrtf(grid_reduce(es, 0.f, 3 + it, 0, false).x / NELF);
      const bool accept = en < 1.0f;
      const float safe = fmaxf(en, 1e-10f);
      float fac = 0.9f * powf(safe, -0.2f);
      fac = accept ? fminf(10.0f, fac) : fmaxf(0.2f, fac);
      if (accept) {
        t = t + hs;
        y = yn;
        fy = k7;
      }
      h = hs * fac;
      done = done || (t >= 1.0f - 1e-7f);
      ++it;
      if (done || it >= 20) break;
    }
  }

  // ---- final phase: out = A_f @ F. Exchange y as K=512 frags in the AF0
  // region (safe: last grid_reduce was a full grid sync; no more basis gemms).
  {
    uint32_t d0 = f2bf(y[0]) | (f2bf(y[1]) << 16);
    uint32_t d1 = f2bf(y[2]) | (f2bf(y[3]) << 16);
    const int kcF = gcq >> 3;
    const int alF = rl | (((gcq >> 1) & 3) << 4);
    unsigned long long* p = YF + ((size_t)(rg * 16 + kcF) * 64 + alF) * 2 + (gcq & 1);
    unsigned long long v = (unsigned long long)d0 | ((unsigned long long)d1 << 32);
    if (fastp) {
      *(volatile unsigned long long*)p = v;
    } else {
      AST(p, v);
    }
  }
  rg_barrier();
  {
    floatx4 a0 = {0.f, 0.f, 0.f, 0.f}, a1 = a0, a2 = a0, a3 = a0;
#pragma unroll
    for (int i = 0; i < 4; ++i) {
      UB2 a;
      const size_t base = ((size_t)(rg * 16 + 4 * w + i) * 64 + lane) * 2;
      if (fastp) {
        a.x = ld128_x(YF + base);
      } else {
        a.q[0] = ALD(YF + base);
        a.q[1] = ALD(YF + base + 1);
      }
      UB b;
      b.u = *(const uint4*)(BfF + (((size_t)(cb * 4 + 0) * 16 + 4 * w + i) * 64 + lane) * 8);
      a0 = __builtin_amdgcn_mfma_f32_16x16x32_bf16(a.v, b.v, a0, 0, 0, 0);
      b.u = *(const uint4*)(BfF + (((size_t)(cb * 4 + 1) * 16 + 4 * w + i) * 64 + lane) * 8);
      a1 = __builtin_amdgcn_mfma_f32_16x16x32_bf16(a.v, b.v, a1, 0, 0, 0);
      b.u = *(const uint4*)(BfF + (((size_t)(cb * 4 + 2) * 16 + 4 * w + i) * 64 + lane) * 8);
      a2 = __builtin_amdgcn_mfma_f32_16x16x32_bf16(a.v, b.v, a2, 0, 0, 0);
      b.u = *(const uint4*)(BfF + (((size_t)(cb * 4 + 3) * 16 + 4 * w + i) * 64 + lane) * 8);
      a3 = __builtin_amdgcn_mfma_f32_16x16x32_bf16(a.v, b.v, a3, 0, 0, 0);
    }
    floatx4 o = reduce4(a0, a1, a2, a3);
    *(floatx4*)(out + (size_t)(rg * 16 + rl) * NDT + cb * 64 + (tid >> 4) * 4) = o;
  }
}

extern "C" void kernel_launch(void* const* d_in, const int* in_sizes, int n_in,
                              void* d_out, int out_size, void* d_ws, size_t ws_size,
                              hipStream_t stream) {
  (void)in_sizes; (void)n_in; (void)out_size; (void)ws_size;
  const float* x = (const float*)d_in[0];
  const float* P = (const float*)d_in[1];
  const float* C = (const float*)d_in[2];
  const float* F = (const float*)d_in[3];
  float* out = (float*)d_out;
  float* ws = (float*)d_ws;

  // pack C/P/F -> bf16 frags, zero ctl+PART1 region (block 0)
  hipLaunchKernelGGL(pack_all, dim3(768), dim3(256), 0, stream, C, P, F,
                     (__bf16*)(ws + BFC_OFF), (unsigned*)(ws + BFP_OFF),
                     (unsigned*)(ws + BFF_OFF), (unsigned*)ws);
  // fused kernel: A0 + RK45 + out (plain launch, hybrid hint+truth barriers)
  hipLaunchKernelGGL(ode_mfma, dim3(256), dim3(256), 0, stream, x, out, ws);
}

// Round 10
// 132.137 us; speedup vs baseline: 1.1179x; 1.1179x over previous
//
#include <hip/hip_runtime.h>
#include <cmath>

typedef float floatx4 __attribute__((ext_vector_type(4)));
typedef __bf16 bf16x8 __attribute__((ext_vector_type(8)));
typedef unsigned uintx4 __attribute__((ext_vector_type(4)));

#define NDT 512
#define NELF 262144.0f

// ---- ws layout (float idx) ----
// FLAG    uint [0..2048)    at (rg*8+cb)*8 — AGENT scope (rg round flag,
//                            XCC exchange at +4). Proven transport (R2/R6/R8).
// [2048..4096) reserved (zeroed, unused)
// PART1 float [4096..10240) at sa*256 + blk — grid-reduce partials, agent
//                            scope, data-as-flag (proven R6/R8); polls batched
//                            (R10): issue all slot loads per iteration instead
//                            of 4 sequential detect chains.
// AF0 16384, AF1 16384+262144 (basis parity buffers, bf16 1 MiB each)
// YF reuses AF0 region after the final grid-wide reduce.
#define AF0_OFF 16384
#define AF1_OFF (16384 + 262144)
#define BFC_OFF (16384 + 2 * 262144)
#define BFP_OFF (BFC_OFF + 262144)
#define BFF_OFF (BFP_OFF + 131072)

#define RTOLc 1e-3f
#define ATOLc 1e-6f
#define TAc 1.0f
#define TBc 1.0f
#define TCc 0.0f

union UB { uint4 u; bf16x8 v; };
union UB2 { unsigned long long q[2]; uint4 u; bf16x8 v; uintx4 x; };

__device__ __forceinline__ uint32_t f2bf(float f) {
  uint32_t u = __float_as_uint(f);
  return (u + 0x7fffu + ((u >> 16) & 1u)) >> 16;
}

#define AST(p, v) __hip_atomic_store((p), (v), __ATOMIC_RELAXED, __HIP_MEMORY_SCOPE_AGENT)
#define ALD(p) __hip_atomic_load((p), __ATOMIC_RELAXED, __HIP_MEMORY_SCOPE_AGENT)

// L1-bypass load (sc0): serves from the XCD's L2. Data path proven (R2/R6/R8).
__device__ __forceinline__ uintx4 ld128_x(const void* p) {
  uintx4 r;
  asm volatile("global_load_dwordx4 %0, %1, off sc0\n\ts_waitcnt vmcnt(0)"
               : "=v"(r) : "v"(p) : "memory");
  return r;
}

// ---- pack: C (coalesced-read/scatter-write, proven) + P/F gather-style; zero ctl ----
__global__ __launch_bounds__(256) void pack_all(const float* __restrict__ C,
                                                const float* __restrict__ P,
                                                const float* __restrict__ F,
                                                __bf16* __restrict__ BfC,
                                                unsigned* __restrict__ BfP,
                                                unsigned* __restrict__ BfF,
                                                unsigned* __restrict__ ctl) {
  const int bid = blockIdx.x, tid = threadIdx.x;
  if (bid == 0) {
    for (int i = tid; i < 10240; i += 256) ctl[i] = 0u;  // FLAG + reserved + PART1
  }
  if (bid < 512) {
    int t = bid * 256 + tid;
    int i = t >> 8;
    int pr = t & 255;  // K0 = pr*4
    floatx4 v = *(const floatx4*)(C + (size_t)i * 1024 + pr * 4);
    uint32_t w0 = f2bf(v[0]) | (f2bf(v[1]) << 16);
    uint32_t w1 = f2bf(v[2]) | (f2bf(v[3]) << 16);
    int c0 = i >> 4;
    int kc = pr >> 3;
    int lq = (pr >> 1) & 3;
    int ln = (i & 15) | (lq << 4);
    int jp = (pr & 1) * 4;
    uint2 val; val.x = w0; val.y = w1;
    *(uint2*)(BfC + ((size_t)(c0 * 32 + kc) * 64 + ln) * 8 + jp) = val;
  } else {
    // gather-style: one thread builds one 16-B frag line (8 bf16 along K)
    const float* M = (bid < 640) ? P : F;
    unsigned* Bf = (bid < 640) ? BfP : BfF;
    int t = ((bid < 640) ? (bid - 512) : (bid - 640)) * 256 + tid;  // 0..32767
    int lane = t & 63;
    int kc = (t >> 6) & 15;
    int nf = t >> 10;
    int n = nf * 16 + (lane & 15);
    int K0 = kc * 32 + ((lane >> 4) & 3) * 8;
    const float* mp = M + (size_t)K0 * NDT + n;
    uint32_t e0 = f2bf(mp[0]);
    uint32_t e1 = f2bf(mp[512]);
    uint32_t e2 = f2bf(mp[1024]);
    uint32_t e3 = f2bf(mp[1536]);
    uint32_t e4 = f2bf(mp[2048]);
    uint32_t e5 = f2bf(mp[2560]);
    uint32_t e6 = f2bf(mp[3072]);
    uint32_t e7 = f2bf(mp[3584]);
    *(uint4*)(Bf + ((size_t)(nf * 16 + kc) * 64 + lane) * 4) =
        make_uint4(e0 | (e1 << 16), e2 | (e3 << 16), e4 | (e5 << 16), e6 | (e7 << 16));
  }
}

// ---- fused kernel: A0 GEMM + RK45 + out GEMM; plain launch, co-residency by
// capacity (grid=256=CU count, launch_bounds(256,1), ~52 KB LDS). ----
__global__ __launch_bounds__(256, 1) void ode_mfma(const float* __restrict__ x,
                                                   float* __restrict__ out,
                                                   float* __restrict__ ws) {
  // double-buffered cross-wave reduction scratch (R8): parity alternates per
  // call, making the leading __syncthreads of the classic reduce redundant.
  __shared__ __align__(16) float red[2][4][16][68];
  __shared__ __align__(16) unsigned short ldsX[16 * 64 * 8];  // 16 KiB
  __shared__ float bred[4];
  __shared__ float shb0s, shb1s;
  __shared__ unsigned sxc[8];

  unsigned* FLAG = (unsigned*)ws;               // agent-scope rg flags (+XCC at +4)
  float* PART1 = ws + 4096;                     // sa*256 + blk (data-as-flag)
  unsigned long long* AfA = (unsigned long long*)(ws + AF0_OFF);
  unsigned long long* AfB = (unsigned long long*)(ws + AF1_OFF);
  unsigned long long* YF = (unsigned long long*)(ws + AF0_OFF);  // reused post-loop
  const __bf16* Bf = (const __bf16*)(ws + BFC_OFF);
  const __bf16* BfP = (const __bf16*)(ws + BFP_OFF);
  const __bf16* BfF = (const __bf16*)(ws + BFF_OFF);

  const int tid = threadIdx.x;
  const int lane = tid & 63;
  const int w = tid >> 6;          // wave id = K-chunk
  const int cb = blockIdx.x >> 5;  // col-slice 64*cb..64*cb+63
  const int rg = blockIdx.x & 31;  // rows 16*rg..16*rg+15
  const int rl = tid & 15;         // owned row
  const int gcq = cb * 16 + (tid >> 4);  // owned global col-quad
  const int blk = rg * 8 + cb;     // flag slot id

  // ---- one-round XCC_ID exchange through the proven agent flag array ----
  bool fastp;
  {
    unsigned myxcc;
    asm volatile("s_getreg_b32 %0, hwreg(HW_REG_XCC_ID)" : "=s"(myxcc));
    myxcc &= 15u;
    if (tid == 0) AST(&FLAG[blk * 8 + 4], myxcc + 1u);
    if (tid < 8) {
      unsigned v;
      while ((v = ALD(&FLAG[(rg * 8 + tid) * 8 + 4])) == 0u) __builtin_amdgcn_s_sleep(1);
      sxc[tid] = v;
    }
    __syncthreads();
    fastp = true;
#pragma unroll
    for (int i = 0; i < 8; ++i) fastp = fastp && (sxc[i] == sxc[0]);
  }

  // persistent register-resident C-frags (K=1024): wave w owns kc 8w..8w+7
  UB Breg[4][8];
#pragma unroll
  for (int cf = 0; cf < 4; ++cf)
#pragma unroll
    for (int i = 0; i < 8; ++i)
      Breg[cf][i].u =
          *(const uint4*)(Bf + (((size_t)(cb * 4 + cf) * 32 + 8 * w + i) * 64 + lane) * 8);

  int rg_phase = 0, par = 0, r4p = 0;

  // arrive: 1 flag store; wait: wave 0's 8 lanes poll the 8 same-rg flags in
  // parallel (agent scope — byte-identical to the R2/R6/R8-proven barrier;
  // R7/R9 showed any extra load in this poll loop regresses)
  auto rg_barrier = [&]() {
    __syncthreads();  // compiler emits s_waitcnt vmcnt(0) before s_barrier
    ++rg_phase;
    if (tid == 0) AST(&FLAG[blk * 8], (unsigned)rg_phase);
    if (tid < 8) {
      while (ALD(&FLAG[(rg * 8 + tid) * 8]) < (unsigned)rg_phase) __builtin_amdgcn_s_sleep(1);
    }
    __syncthreads();
  };

  // cross-wave K-reduction (parity double-buffered, single barrier — R8)
  auto reduce4 = [&](floatx4 a0, floatx4 a1, floatx4 a2, floatx4 a3) -> floatx4 {
    const int p = r4p;
    r4p ^= 1;
    const int q = lane >> 4, l4 = lane & 15;
#pragma unroll
    for (int ri = 0; ri < 4; ++ri) {
      red[p][w][4 * q + ri][l4] = a0[ri];
      red[p][w][4 * q + ri][16 + l4] = a1[ri];
      red[p][w][4 * q + ri][32 + l4] = a2[ri];
      red[p][w][4 * q + ri][48 + l4] = a3[ri];
    }
    __syncthreads();
    const int c0 = (tid >> 4) * 4;
    floatx4 o = *(const floatx4*)&red[p][0][rl][c0];
    o += *(const floatx4*)&red[p][1][rl][c0];
    o += *(const floatx4*)&red[p][2][rl][c0];
    o += *(const floatx4*)&red[p][3][rl][c0];
    return o;
  };

  // basis write slot (K=1024 frag layout, sin/cos interleaved over K=2*col)
  const int kcw = gcq >> 2;
  const int alw = rl | ((gcq & 3) << 4);
  const size_t wslot = ((size_t)(rg * 32 + kcw) * 64 + alw) * 2;

  auto write_basis = [&](floatx4 av_, float targ) {
    uint32_t d[4];
#pragma unroll
    for (int e = 0; e < 4; ++e) {
      float s, c;
      __sincosf(TAc * av_[e] + targ, &s, &c);
      d[e] = f2bf(s) | (f2bf(c) << 16);
    }
    unsigned long long* Ap = (par ? AfB : AfA) + wslot;
    if (fastp) {
      uintx4 u = {d[0], d[1], d[2], d[3]};
      *(volatile uintx4*)Ap = u;  // plain write-through store -> XCD L2
    } else {
      AST(Ap, (unsigned long long)d[0] | ((unsigned long long)d[1] << 32));
      AST(Ap + 1, (unsigned long long)d[2] | ((unsigned long long)d[3] << 32));
    }
  };

  auto gemm = [&]() -> floatx4 {
    const unsigned long long* Ap =
        (par ? AfB : AfA) + ((size_t)(rg * 32 + 8 * w) * 64 + lane) * 2;
    UB2 a[8];
    floatx4 acc0 = {0.f, 0.f, 0.f, 0.f}, acc1 = acc0, acc2 = acc0, acc3 = acc0;
    if (fastp) {
      // 8 batched 16B sc0 loads; split waitcnt: vmcnt(4) releases frags 0-3
      // (MFMA overlaps in-flight frags 4-7), vmcnt(0) + sched_barrier(0)
      // fences the rest (rule #18). Proven R8.
      const char* b0 = (const char*)Ap;
      const char* b1 = b0 + 4096;
      uintx4 t0, t1, t2, t3, t4, t5, t6, t7;
      asm volatile(
          "global_load_dwordx4 %0, %4, off sc0\n\t"
          "global_load_dwordx4 %1, %4, off offset:1024 sc0\n\t"
          "global_load_dwordx4 %2, %4, off offset:2048 sc0\n\t"
          "global_load_dwordx4 %3, %4, off offset:3072 sc0"
          : "=&v"(t0), "=&v"(t1), "=&v"(t2), "=&v"(t3)
          : "v"(b0)
          : "memory");
      asm volatile(
          "global_load_dwordx4 %0, %4, off sc0\n\t"
          "global_load_dwordx4 %1, %4, off offset:1024 sc0\n\t"
          "global_load_dwordx4 %2, %4, off offset:2048 sc0\n\t"
          "global_load_dwordx4 %3, %4, off offset:3072 sc0\n\t"
          "s_waitcnt vmcnt(4)"
          : "=&v"(t4), "=&v"(t5), "=&v"(t6), "=&v"(t7)
          : "v"(b1)
          : "memory");
      __builtin_amdgcn_sched_barrier(0);
      a[0].x = t0; a[1].x = t1; a[2].x = t2; a[3].x = t3;
#pragma unroll
      for (int i = 0; i < 4; ++i) {
        acc0 = __builtin_amdgcn_mfma_f32_16x16x32_bf16(a[i].v, Breg[0][i].v, acc0, 0, 0, 0);
        acc1 = __builtin_amdgcn_mfma_f32_16x16x32_bf16(a[i].v, Breg[1][i].v, acc1, 0, 0, 0);
        acc2 = __builtin_amdgcn_mfma_f32_16x16x32_bf16(a[i].v, Breg[2][i].v, acc2, 0, 0, 0);
        acc3 = __builtin_amdgcn_mfma_f32_16x16x32_bf16(a[i].v, Breg[3][i].v, acc3, 0, 0, 0);
      }
      asm volatile("s_waitcnt vmcnt(0)" ::: "memory");
      __builtin_amdgcn_sched_barrier(0);
      a[4].x = t4; a[5].x = t5; a[6].x = t6; a[7].x = t7;
#pragma unroll
      for (int i = 4; i < 8; ++i) {
        acc0 = __builtin_amdgcn_mfma_f32_16x16x32_bf16(a[i].v, Breg[0][i].v, acc0, 0, 0, 0);
        acc1 = __builtin_amdgcn_mfma_f32_16x16x32_bf16(a[i].v, Breg[1][i].v, acc1, 0, 0, 0);
        acc2 = __builtin_amdgcn_mfma_f32_16x16x32_bf16(a[i].v, Breg[2][i].v, acc2, 0, 0, 0);
        acc3 = __builtin_amdgcn_mfma_f32_16x16x32_bf16(a[i].v, Breg[3][i].v, acc3, 0, 0, 0);
      }
    } else {
#pragma unroll
      for (int i = 0; i < 8; ++i) {
        a[i].q[0] = ALD(Ap + (size_t)i * 128);
        a[i].q[1] = ALD(Ap + (size_t)i * 128 + 1);
      }
#pragma unroll
      for (int i = 0; i < 8; ++i) {
        acc0 = __builtin_amdgcn_mfma_f32_16x16x32_bf16(a[i].v, Breg[0][i].v, acc0, 0, 0, 0);
        acc1 = __builtin_amdgcn_mfma_f32_16x16x32_bf16(a[i].v, Breg[1][i].v, acc1, 0, 0, 0);
        acc2 = __builtin_amdgcn_mfma_f32_16x16x32_bf16(a[i].v, Breg[2][i].v, acc2, 0, 0, 0);
        acc3 = __builtin_amdgcn_mfma_f32_16x16x32_bf16(a[i].v, Breg[3][i].v, acc3, 0, 0, 0);
      }
    }
    par ^= 1;
    return reduce4(acc0, acc1, acc2, acc3);
  };

  auto block_sum = [&](float v) -> float {
#pragma unroll
    for (int o = 32; o; o >>= 1) v += __shfl_down(v, o, 64);
    __syncthreads();
    if (lane == 0) bred[w] = v;
    __syncthreads();
    return (tid == 0) ? (bred[0] + bred[1] + bred[2] + bred[3]) : 0.0f;
  };

  // single-level deterministic grid reduce (agent scope; data-as-flag, R6/R8).
  // R10: BATCHED polling — all slot loads issued per iteration (single detect
  // round-trip) instead of 4 (or 8) sequential while-loop detect chains.
  auto grid_reduce = [&](float va, float vb, int sa, int sb, bool two) -> float2 {
    float ba = block_sum(va);
    float bb = two ? block_sum(vb) : 0.0f;
    if (tid == 0) {
      AST((unsigned*)&PART1[sa * 256 + blk], __float_as_uint(ba) | 1u);
      if (two) AST((unsigned*)&PART1[sb * 256 + blk], __float_as_uint(bb) | 1u);
    }
    if (w == 0) {
      const unsigned* pa = (const unsigned*)&PART1[sa * 256 + lane];
      const unsigned* pb = (const unsigned*)&PART1[sb * 256 + lane];
      unsigned ua0, ua1, ua2, ua3, ub0 = 1u, ub1 = 1u, ub2 = 1u, ub3 = 1u;
      while (true) {
        ua0 = ALD(pa);
        ua1 = ALD(pa + 64);
        ua2 = ALD(pa + 128);
        ua3 = ALD(pa + 192);
        if (two) {
          ub0 = ALD(pb);
          ub1 = ALD(pb + 64);
          ub2 = ALD(pb + 128);
          ub3 = ALD(pb + 192);
        }
        if ((ua0 & ua1 & ua2 & ua3 & ub0 & ub1 & ub2 & ub3) != 0u ||
            (ua0 && ua1 && ua2 && ua3 && ub0 && ub1 && ub2 && ub3)) break;
        __builtin_amdgcn_s_sleep(1);
      }
      float x0 = __uint_as_float(ua0) + __uint_as_float(ua1) +
                 __uint_as_float(ua2) + __uint_as_float(ua3);
      float x1 = 0.0f;
      if (two)
        x1 = __uint_as_float(ub0) + __uint_as_float(ub1) +
             __uint_as_float(ub2) + __uint_as_float(ub3);
#pragma unroll
      for (int o = 32; o; o >>= 1) {
        x0 += __shfl_down(x0, o, 64);
        x1 += __shfl_down(x1, o, 64);
      }
      if (lane == 0) { shb0s = x0; shb1s = x1; }
    }
    __syncthreads();
    return make_float2(shb0s, shb1s);
  };

  // ---- phase A0: y = (x @ P) patch, K=512 MFMA vs pre-packed P-frags ----
  floatx4 y, fy, k2, k3, k4, k5, k6, k7, yn, av;
  {
    for (int idx = tid; idx < 8192; idx += 256) {
      int r = idx >> 9, k = idx & 511;
      float v = x[(size_t)(rg * 16 + r) * NDT + k];
      int al = r | (((k >> 3) & 3) << 4);
      ldsX[((size_t)(k >> 5) * 64 + al) * 8 + (k & 7)] = (unsigned short)f2bf(v);
    }
    __syncthreads();
    floatx4 a0 = {0.f, 0.f, 0.f, 0.f}, a1 = a0, a2 = a0, a3 = a0;
#pragma unroll
    for (int i = 0; i < 4; ++i) {
      UB a, b;
      a.u = *(const uint4*)(ldsX + ((size_t)(4 * w + i) * 64 + lane) * 8);
      b.u = *(const uint4*)(BfP + (((size_t)(cb * 4 + 0) * 16 + 4 * w + i) * 64 + lane) * 8);
      a0 = __builtin_amdgcn_mfma_f32_16x16x32_bf16(a.v, b.v, a0, 0, 0, 0);
      b.u = *(const uint4*)(BfP + (((size_t)(cb * 4 + 1) * 16 + 4 * w + i) * 64 + lane) * 8);
      a1 = __builtin_amdgcn_mfma_f32_16x16x32_bf16(a.v, b.v, a1, 0, 0, 0);
      b.u = *(const uint4*)(BfP + (((size_t)(cb * 4 + 2) * 16 + 4 * w + i) * 64 + lane) * 8);
      a2 = __builtin_amdgcn_mfma_f32_16x16x32_bf16(a.v, b.v, a2, 0, 0, 0);
      b.u = *(const uint4*)(BfP + (((size_t)(cb * 4 + 3) * 16 + 4 * w + i) * 64 + lane) * 8);
      a3 = __builtin_amdgcn_mfma_f32_16x16x32_bf16(a.v, b.v, a3, 0, 0, 0);
    }
    y = reduce4(a0, a1, a2, a3);
  }

  // ---- initial step selection (scipy _select_initial_step) ----
  write_basis(y, TCc + TBc * 0.0f);
  rg_barrier();
  fy = gemm();  // f0
  {
    float s0 = 0.f, s1 = 0.f;
#pragma unroll
    for (int r = 0; r < 4; ++r) {
      float sv = ATOLc + RTOLc * fabsf(y[r]);
      float a = y[r] / sv, b = fy[r] / sv;
      s0 += a * a;
      s1 += b * b;
    }
    float2 d01 = grid_reduce(s0, s1, 0, 1, true);
    const float d0 = sqrtf(d01.x / NELF);
    const float d1 = sqrtf(d01.y / NELF);
    const float h0 = (d0 < 1e-5f || d1 < 1e-5f) ? 1e-6f : 0.01f * d0 / d1;
    av = y + h0 * fy;
    write_basis(av, TCc + TBc * h0);
    rg_barrier();
    k2 = gemm();  // f1 (temp)
    float s2 = 0.f;
#pragma unroll
    for (int r = 0; r < 4; ++r) {
      float sv = ATOLc + RTOLc * fabsf(y[r]);
      float dd = (k2[r] - fy[r]) / sv;
      s2 += dd * dd;
    }
    const float d2 = sqrtf(grid_reduce(s2, 0.f, 2, 0, false).x / NELF) / h0;
    const float dmax = fmaxf(d1, d2);
    const float h1i = (dmax <= 1e-15f) ? fmaxf(1e-6f, h0 * 1e-3f) : powf(0.01f / dmax, 0.2f);
    float h = fminf(fminf(100.0f * h0, h1i), 1.0f);
    float t = 0.0f;
    bool done = false;
    int it = 0;

    const float a21 = (float)(1.0 / 5.0);
    const float a31 = (float)(3.0 / 40.0), a32 = (float)(9.0 / 40.0);
    const float a41 = (float)(44.0 / 45.0), a42 = (float)(-56.0 / 15.0), a43 = (float)(32.0 / 9.0);
    const float a51 = (float)(19372.0 / 6561.0), a52 = (float)(-25360.0 / 2187.0),
                a53 = (float)(64448.0 / 6561.0), a54 = (float)(-212.0 / 729.0);
    const float a61 = (float)(9017.0 / 3168.0), a62 = (float)(-355.0 / 33.0),
                a63 = (float)(46732.0 / 5247.0), a64 = (float)(49.0 / 176.0),
                a65 = (float)(-5103.0 / 18656.0);
    const float b1 = (float)(35.0 / 384.0), b3 = (float)(500.0 / 1113.0),
                b4 = (float)(125.0 / 192.0), b5 = (float)(-2187.0 / 6784.0),
                b6 = (float)(11.0 / 84.0);
    const float e1c = (float)(71.0 / 57600.0), e3c = (float)(-71.0 / 16695.0),
                e4c = (float)(71.0 / 1920.0), e5c = (float)(-17253.0 / 339200.0),
                e6c = (float)(22.0 / 525.0), e7c = (float)(-1.0 / 40.0);
    const float c89 = (float)(8.0 / 9.0);

    while (true) {
      const float hs = fminf(h, 1.0f - t);

      av = y + (hs * a21) * fy;
      write_basis(av, TCc + TBc * (t + 0.2f * hs));
      rg_barrier();
      k2 = gemm();

      av = y + hs * (a31 * fy + a32 * k2);
      write_basis(av, TCc + TBc * (t + 0.3f * hs));
      rg_barrier();
      k3 = gemm();

      av = y + hs * (a41 * fy + a42 * k2 + a43 * k3);
      write_basis(av, TCc + TBc * (t + 0.8f * hs));
      rg_barrier();
      k4 = gemm();

      av = y + hs * (a51 * fy + a52 * k2 + a53 * k3 + a54 * k4);
      write_basis(av, TCc + TBc * (t + c89 * hs));
      rg_barrier();
      k5 = gemm();

      av = y + hs * (a61 * fy + a62 * k2 + a63 * k3 + a64 * k4 + a65 * k5);
      write_basis(av, TCc + TBc * (t + hs));
      rg_barrier();
      k6 = gemm();

      yn = y + hs * (b1 * fy + b3 * k3 + b4 * k4 + b5 * k5 + b6 * k6);
      write_basis(yn, TCc + TBc * (t + hs));  // FSAL stage input
      rg_barrier();
      k7 = gemm();

      float es = 0.f;
#pragma unroll
      for (int r = 0; r < 4; ++r) {
        float errc = hs * (e1c * fy[r] + e3c * k3[r] + e4c * k4[r] + e5c * k5[r] +
                           e6c * k6[r] + e7c * k7[r]);
        float sv = ATOLc + RTOLc * fmaxf(fabsf(y[r]), fabsf(yn[r]));
        float dd = errc / sv;
        es += dd * dd;
      }
      const float en = sqrtf(grid_reduce(es, 0.f, 3 + it, 0, false).x / NELF);
      const bool accept = en < 1.0f;
      const float safe = fmaxf(en, 1e-10f);
      float fac = 0.9f * powf(safe, -0.2f);
      fac = accept ? fminf(10.0f, fac) : fmaxf(0.2f, fac);
      if (accept) {
        t = t + hs;
        y = yn;
        fy = k7;
      }
      h = hs * fac;
      done = done || (t >= 1.0f - 1e-7f);
      ++it;
      if (done || it >= 20) break;
    }
  }

  // ---- final phase: out = A_f @ F. Exchange y as K=512 frags in the AF0
  // region (safe: last grid_reduce was a full grid sync; no more basis gemms).
  {
    uint32_t d0 = f2bf(y[0]) | (f2bf(y[1]) << 16);
    uint32_t d1 = f2bf(y[2]) | (f2bf(y[3]) << 16);
    const int kcF = gcq >> 3;
    const int alF = rl | (((gcq >> 1) & 3) << 4);
    unsigned long long* p = YF + ((size_t)(rg * 16 + kcF) * 64 + alF) * 2 + (gcq & 1);
    unsigned long long v = (unsigned long long)d0 | ((unsigned long long)d1 << 32);
    if (fastp) {
      *(volatile unsigned long long*)p = v;
    } else {
      AST(p, v);
    }
  }
  rg_barrier();
  {
    floatx4 a0 = {0.f, 0.f, 0.f, 0.f}, a1 = a0, a2 = a0, a3 = a0;
#pragma unroll
    for (int i = 0; i < 4; ++i) {
      UB2 a;
      const size_t base = ((size_t)(rg * 16 + 4 * w + i) * 64 + lane) * 2;
      if (fastp) {
        a.x = ld128_x(YF + base);
      } else {
        a.q[0] = ALD(YF + base);
        a.q[1] = ALD(YF + base + 1);
      }
      UB b;
      b.u = *(const uint4*)(BfF + (((size_t)(cb * 4 + 0) * 16 + 4 * w + i) * 64 + lane) * 8);
      a0 = __builtin_amdgcn_mfma_f32_16x16x32_bf16(a.v, b.v, a0, 0, 0, 0);
      b.u = *(const uint4*)(BfF + (((size_t)(cb * 4 + 1) * 16 + 4 * w + i) * 64 + lane) * 8);
      a1 = __builtin_amdgcn_mfma_f32_16x16x32_bf16(a.v, b.v, a1, 0, 0, 0);
      b.u = *(const uint4*)(BfF + (((size_t)(cb * 4 + 2) * 16 + 4 * w + i) * 64 + lane) * 8);
      a2 = __builtin_amdgcn_mfma_f32_16x16x32_bf16(a.v, b.v, a2, 0, 0, 0);
      b.u = *(const uint4*)(BfF + (((size_t)(cb * 4 + 3) * 16 + 4 * w + i) * 64 + lane) * 8);
      a3 = __builtin_amdgcn_mfma_f32_16x16x32_bf16(a.v, b.v, a3, 0, 0, 0);
    }
    floatx4 o = reduce4(a0, a1, a2, a3);
    *(floatx4*)(out + (size_t)(rg * 16 + rl) * NDT + cb * 64 + (tid >> 4) * 4) = o;
  }
}

extern "C" void kernel_launch(void* const* d_in, const int* in_sizes, int n_in,
                              void* d_out, int out_size, void* d_ws, size_t ws_size,
                              hipStream_t stream) {
  (void)in_sizes; (void)n_in; (void)out_size; (void)ws_size;
  const float* x = (const float*)d_in[0];
  const float* P = (const float*)d_in[1];
  const float* C = (const float*)d_in[2];
  const float* F = (const float*)d_in[3];
  float* out = (float*)d_out;
  float* ws = (float*)d_ws;

  // pack C/P/F -> bf16 frags, zero ctl+PART1 region (block 0)
  hipLaunchKernelGGL(pack_all, dim3(768), dim3(256), 0, stream, C, P, F,
                     (__bf16*)(ws + BFC_OFF), (unsigned*)(ws + BFP_OFF),
                     (unsigned*)(ws + BFF_OFF), (unsigned*)ws);
  // fused kernel: A0 + RK45 + out (plain launch, flag barriers, 1-level reduce)
  hipLaunchKernelGGL(ode_mfma, dim3(256), dim3(256), 0, stream, x, out, ws);
}

// Round 11
// 131.938 us; speedup vs baseline: 1.1195x; 1.0015x over previous
//
#include <hip/hip_runtime.h>
#include <cmath>

typedef float floatx4 __attribute__((ext_vector_type(4)));
typedef __bf16 bf16x8 __attribute__((ext_vector_type(8)));
typedef unsigned uintx4 __attribute__((ext_vector_type(4)));

#define NDT 512
#define NELF 262144.0f

// ---- ws layout (float idx) ----
// FLAG    uint [0..2048)    at (rg*8+cb)*8 — AGENT scope. +0 rg round flag,
//                            +4 XCC exchange, +5 pack-done. Zeroed by the
//                            hipMemsetAsync node before the kernel.
// [2048..4096) reserved (zeroed, unused)
// PART1 float [4096..10240) at sa*256 + blk — grid-reduce partials, agent
//                            scope, data-as-flag, batched polls (R10).
// AF0 16384, AF1 16384+262144 (basis parity buffers, bf16 1 MiB each)
// YF reuses AF0 region after the final grid-wide reduce.
#define AF0_OFF 16384
#define AF1_OFF (16384 + 262144)
#define BFC_OFF (16384 + 2 * 262144)
#define BFP_OFF (BFC_OFF + 262144)
#define BFF_OFF (BFP_OFF + 131072)

#define RTOLc 1e-3f
#define ATOLc 1e-6f
#define TAc 1.0f
#define TBc 1.0f
#define TCc 0.0f

union UB { uint4 u; bf16x8 v; };
union UB2 { unsigned long long q[2]; uint4 u; bf16x8 v; uintx4 x; };

__device__ __forceinline__ uint32_t f2bf(float f) {
  uint32_t u = __float_as_uint(f);
  return (u + 0x7fffu + ((u >> 16) & 1u)) >> 16;
}

#define AST(p, v) __hip_atomic_store((p), (v), __ATOMIC_RELAXED, __HIP_MEMORY_SCOPE_AGENT)
#define ALD(p) __hip_atomic_load((p), __ATOMIC_RELAXED, __HIP_MEMORY_SCOPE_AGENT)

// L1-bypass load (sc0): serves from the XCD's L2. Data path proven (R2/R6/R8).
__device__ __forceinline__ uintx4 ld128_x(const void* p) {
  uintx4 r;
  asm volatile("global_load_dwordx4 %0, %1, off sc0\n\ts_waitcnt vmcnt(0)"
               : "=v"(r) : "v"(p) : "memory");
  return r;
}

// ---- fused kernel: pack C/P/F + A0 GEMM + RK45 + out GEMM. Single launch;
// grid 256 = CU count, launch_bounds(256,1), ~52 KB LDS. Pack outputs use
// AGENT stores (the old pack_all->ode kernel boundary's L2 flush is gone;
// plain stores would sit dirty in the packer's XCD L2 and be invisible
// cross-XCD). Pack-done rendezvous = R10's proven batched 256-slot detect. ----
__global__ __launch_bounds__(256, 1) void ode_fused(const float* __restrict__ x,
                                                    const float* __restrict__ C,
                                                    const float* __restrict__ P,
                                                    const float* __restrict__ F,
                                                    float* __restrict__ out,
                                                    float* ws) {
  // double-buffered cross-wave reduction scratch (R8): parity alternates per
  // call, making the leading __syncthreads of the classic reduce redundant.
  __shared__ __align__(16) float red[2][4][16][68];
  __shared__ __align__(16) unsigned short ldsX[16 * 64 * 8];  // 16 KiB
  __shared__ float bred[4];
  __shared__ float shb0s, shb1s;
  __shared__ unsigned sxc[8];

  unsigned* FLAG = (unsigned*)ws;               // agent-scope flags
  float* PART1 = ws + 4096;                     // sa*256 + blk (data-as-flag)
  unsigned long long* AfA = (unsigned long long*)(ws + AF0_OFF);
  unsigned long long* AfB = (unsigned long long*)(ws + AF1_OFF);
  unsigned long long* YF = (unsigned long long*)(ws + AF0_OFF);  // reused post-loop
  const __bf16* Bf = (const __bf16*)(ws + BFC_OFF);
  const __bf16* BfP = (const __bf16*)(ws + BFP_OFF);
  const __bf16* BfF = (const __bf16*)(ws + BFF_OFF);

  const int tid = threadIdx.x;
  const int lane = tid & 63;
  const int w = tid >> 6;          // wave id = K-chunk
  const int cb = blockIdx.x >> 5;  // col-slice 64*cb..64*cb+63
  const int rg = blockIdx.x & 31;  // rows 16*rg..16*rg+15
  const int rl = tid & 15;         // owned row
  const int gcq = cb * 16 + (tid >> 4);  // owned global col-quad
  const int blk = rg * 8 + cb;     // flag slot id

  // ---- pack phase: C (2 chunks/block) + P-or-F (1 frag line/thread) ----
  {
    __bf16* BfCw = (__bf16*)(ws + BFC_OFF);
    unsigned* Bfw = (blockIdx.x < 128) ? (unsigned*)(ws + BFP_OFF)
                                       : (unsigned*)(ws + BFF_OFF);
#pragma unroll
    for (int rep = 0; rep < 2; ++rep) {
      int i = blockIdx.x * 2 + rep;  // C chunk 0..511
      int pr = tid;
      floatx4 v = *(const floatx4*)(C + (size_t)i * 1024 + pr * 4);
      uint32_t e0 = f2bf(v[0]) | (f2bf(v[1]) << 16);
      uint32_t e1 = f2bf(v[2]) | (f2bf(v[3]) << 16);
      int c0 = i >> 4;
      int kc = pr >> 3;
      int lq = (pr >> 1) & 3;
      int ln = (i & 15) | (lq << 4);
      int jp = (pr & 1) * 4;
      unsigned long long val = (unsigned long long)e0 | ((unsigned long long)e1 << 32);
      AST((unsigned long long*)(BfCw + ((size_t)(c0 * 32 + kc) * 64 + ln) * 8 + jp), val);
    }
    {
      const float* M = (blockIdx.x < 128) ? P : F;
      int t = ((blockIdx.x < 128) ? blockIdx.x : (blockIdx.x - 128)) * 256 + tid;
      int ln_ = t & 63;
      int kc = (t >> 6) & 15;
      int nf = t >> 10;
      int n = nf * 16 + (ln_ & 15);
      int K0 = kc * 32 + ((ln_ >> 4) & 3) * 8;
      const float* mp = M + (size_t)K0 * NDT + n;
      uint32_t e0 = f2bf(mp[0]);
      uint32_t e1 = f2bf(mp[512]);
      uint32_t e2 = f2bf(mp[1024]);
      uint32_t e3 = f2bf(mp[1536]);
      uint32_t e4 = f2bf(mp[2048]);
      uint32_t e5 = f2bf(mp[2560]);
      uint32_t e6 = f2bf(mp[3072]);
      uint32_t e7 = f2bf(mp[3584]);
      unsigned long long v0 =
          (unsigned long long)(e0 | (e1 << 16)) | ((unsigned long long)(e2 | (e3 << 16)) << 32);
      unsigned long long v1 =
          (unsigned long long)(e4 | (e5 << 16)) | ((unsigned long long)(e6 | (e7 << 16)) << 32);
      unsigned long long* dst =
          (unsigned long long*)(Bfw + ((size_t)(nf * 16 + kc) * 64 + ln_) * 4);
      AST(dst, v0);
      AST(dst + 1, v1);
    }
  }

  // ---- ldsX staging for A0 (local; overlaps pack-store drain) ----
  for (int idx = tid; idx < 8192; idx += 256) {
    int r = idx >> 9, k = idx & 511;
    float v = x[(size_t)(rg * 16 + r) * NDT + k];
    int al = r | (((k >> 3) & 3) << 4);
    ldsX[((size_t)(k >> 5) * 64 + al) * 8 + (k & 7)] = (unsigned short)f2bf(v);
  }
  __syncthreads();  // drains pack agent-stores (vmcnt) + ldsX writes (lgkmcnt)

  // ---- pack-done grid rendezvous: post +5, wave-0 batched 256-slot detect
  // (same shape as the R10-proven grid_reduce detect) ----
  {
    if (tid == 0) AST(&FLAG[blk * 8 + 5], 1u);
    if (w == 0) {
      while (true) {
        unsigned a0 = ALD(&FLAG[(lane + 0) * 8 + 5]);
        unsigned a1 = ALD(&FLAG[(lane + 64) * 8 + 5]);
        unsigned a2 = ALD(&FLAG[(lane + 128) * 8 + 5]);
        unsigned a3 = ALD(&FLAG[(lane + 192) * 8 + 5]);
        if ((a0 & a1 & a2 & a3) != 0u) break;
        __builtin_amdgcn_s_sleep(1);
      }
    }
    __syncthreads();
  }

  // ---- one-round XCC_ID exchange through the proven agent flag array ----
  bool fastp;
  {
    unsigned myxcc;
    asm volatile("s_getreg_b32 %0, hwreg(HW_REG_XCC_ID)" : "=s"(myxcc));
    myxcc &= 15u;
    if (tid == 0) AST(&FLAG[blk * 8 + 4], myxcc + 1u);
    if (tid < 8) {
      unsigned v;
      while ((v = ALD(&FLAG[(rg * 8 + tid) * 8 + 4])) == 0u) __builtin_amdgcn_s_sleep(1);
      sxc[tid] = v;
    }
    __syncthreads();
    fastp = true;
#pragma unroll
    for (int i = 0; i < 8; ++i) fastp = fastp && (sxc[i] == sxc[0]);
  }

  // persistent register-resident C-frags (K=1024): wave w owns kc 8w..8w+7
  UB Breg[4][8];
#pragma unroll
  for (int cf = 0; cf < 4; ++cf)
#pragma unroll
    for (int i = 0; i < 8; ++i)
      Breg[cf][i].u =
          *(const uint4*)(Bf + (((size_t)(cb * 4 + cf) * 32 + 8 * w + i) * 64 + lane) * 8);

  int rg_phase = 0, par = 0, r4p = 0;

  // arrive: 1 flag store; wait: wave 0's 8 lanes poll the 8 same-rg flags in
  // parallel (agent scope — byte-identical to the R2/R6/R8-proven barrier)
  auto rg_barrier = [&]() {
    __syncthreads();  // compiler emits s_waitcnt vmcnt(0) before s_barrier
    ++rg_phase;
    if (tid == 0) AST(&FLAG[blk * 8], (unsigned)rg_phase);
    if (tid < 8) {
      while (ALD(&FLAG[(rg * 8 + tid) * 8]) < (unsigned)rg_phase) __builtin_amdgcn_s_sleep(1);
    }
    __syncthreads();
  };

  // cross-wave K-reduction (parity double-buffered, single barrier — R8)
  auto reduce4 = [&](floatx4 a0, floatx4 a1, floatx4 a2, floatx4 a3) -> floatx4 {
    const int p = r4p;
    r4p ^= 1;
    const int q = lane >> 4, l4 = lane & 15;
#pragma unroll
    for (int ri = 0; ri < 4; ++ri) {
      red[p][w][4 * q + ri][l4] = a0[ri];
      red[p][w][4 * q + ri][16 + l4] = a1[ri];
      red[p][w][4 * q + ri][32 + l4] = a2[ri];
      red[p][w][4 * q + ri][48 + l4] = a3[ri];
    }
    __syncthreads();
    const int c0 = (tid >> 4) * 4;
    floatx4 o = *(const floatx4*)&red[p][0][rl][c0];
    o += *(const floatx4*)&red[p][1][rl][c0];
    o += *(const floatx4*)&red[p][2][rl][c0];
    o += *(const floatx4*)&red[p][3][rl][c0];
    return o;
  };

  // basis write slot (K=1024 frag layout, sin/cos interleaved over K=2*col)
  const int kcw = gcq >> 2;
  const int alw = rl | ((gcq & 3) << 4);
  const size_t wslot = ((size_t)(rg * 32 + kcw) * 64 + alw) * 2;

  auto write_basis = [&](floatx4 av_, float targ) {
    uint32_t d[4];
#pragma unroll
    for (int e = 0; e < 4; ++e) {
      float s, c;
      __sincosf(TAc * av_[e] + targ, &s, &c);
      d[e] = f2bf(s) | (f2bf(c) << 16);
    }
    unsigned long long* Ap = (par ? AfB : AfA) + wslot;
    if (fastp) {
      uintx4 u = {d[0], d[1], d[2], d[3]};
      *(volatile uintx4*)Ap = u;  // plain write-through store -> XCD L2
    } else {
      AST(Ap, (unsigned long long)d[0] | ((unsigned long long)d[1] << 32));
      AST(Ap + 1, (unsigned long long)d[2] | ((unsigned long long)d[3] << 32));
    }
  };

  auto gemm = [&]() -> floatx4 {
    const unsigned long long* Ap =
        (par ? AfB : AfA) + ((size_t)(rg * 32 + 8 * w) * 64 + lane) * 2;
    UB2 a[8];
    floatx4 acc0 = {0.f, 0.f, 0.f, 0.f}, acc1 = acc0, acc2 = acc0, acc3 = acc0;
    if (fastp) {
      // 8 batched 16B sc0 loads; split waitcnt: vmcnt(4) releases frags 0-3
      // (MFMA overlaps in-flight frags 4-7), vmcnt(0) + sched_barrier(0)
      // fences the rest (rule #18). Proven R8.
      const char* b0 = (const char*)Ap;
      const char* b1 = b0 + 4096;
      uintx4 t0, t1, t2, t3, t4, t5, t6, t7;
      asm volatile(
          "global_load_dwordx4 %0, %4, off sc0\n\t"
          "global_load_dwordx4 %1, %4, off offset:1024 sc0\n\t"
          "global_load_dwordx4 %2, %4, off offset:2048 sc0\n\t"
          "global_load_dwordx4 %3, %4, off offset:3072 sc0"
          : "=&v"(t0), "=&v"(t1), "=&v"(t2), "=&v"(t3)
          : "v"(b0)
          : "memory");
      asm volatile(
          "global_load_dwordx4 %0, %4, off sc0\n\t"
          "global_load_dwordx4 %1, %4, off offset:1024 sc0\n\t"
          "global_load_dwordx4 %2, %4, off offset:2048 sc0\n\t"
          "global_load_dwordx4 %3, %4, off offset:3072 sc0\n\t"
          "s_waitcnt vmcnt(4)"
          : "=&v"(t4), "=&v"(t5), "=&v"(t6), "=&v"(t7)
          : "v"(b1)
          : "memory");
      __builtin_amdgcn_sched_barrier(0);
      a[0].x = t0; a[1].x = t1; a[2].x = t2; a[3].x = t3;
#pragma unroll
      for (int i = 0; i < 4; ++i) {
        acc0 = __builtin_amdgcn_mfma_f32_16x16x32_bf16(a[i].v, Breg[0][i].v, acc0, 0, 0, 0);
        acc1 = __builtin_amdgcn_mfma_f32_16x16x32_bf16(a[i].v, Breg[1][i].v, acc1, 0, 0, 0);
        acc2 = __builtin_amdgcn_mfma_f32_16x16x32_bf16(a[i].v, Breg[2][i].v, acc2, 0, 0, 0);
        acc3 = __builtin_amdgcn_mfma_f32_16x16x32_bf16(a[i].v, Breg[3][i].v, acc3, 0, 0, 0);
      }
      asm volatile("s_waitcnt vmcnt(0)" ::: "memory");
      __builtin_amdgcn_sched_barrier(0);
      a[4].x = t4; a[5].x = t5; a[6].x = t6; a[7].x = t7;
#pragma unroll
      for (int i = 4; i < 8; ++i) {
        acc0 = __builtin_amdgcn_mfma_f32_16x16x32_bf16(a[i].v, Breg[0][i].v, acc0, 0, 0, 0);
        acc1 = __builtin_amdgcn_mfma_f32_16x16x32_bf16(a[i].v, Breg[1][i].v, acc1, 0, 0, 0);
        acc2 = __builtin_amdgcn_mfma_f32_16x16x32_bf16(a[i].v, Breg[2][i].v, acc2, 0, 0, 0);
        acc3 = __builtin_amdgcn_mfma_f32_16x16x32_bf16(a[i].v, Breg[3][i].v, acc3, 0, 0, 0);
      }
    } else {
#pragma unroll
      for (int i = 0; i < 8; ++i) {
        a[i].q[0] = ALD(Ap + (size_t)i * 128);
        a[i].q[1] = ALD(Ap + (size_t)i * 128 + 1);
      }
#pragma unroll
      for (int i = 0; i < 8; ++i) {
        acc0 = __builtin_amdgcn_mfma_f32_16x16x32_bf16(a[i].v, Breg[0][i].v, acc0, 0, 0, 0);
        acc1 = __builtin_amdgcn_mfma_f32_16x16x32_bf16(a[i].v, Breg[1][i].v, acc1, 0, 0, 0);
        acc2 = __builtin_amdgcn_mfma_f32_16x16x32_bf16(a[i].v, Breg[2][i].v, acc2, 0, 0, 0);
        acc3 = __builtin_amdgcn_mfma_f32_16x16x32_bf16(a[i].v, Breg[3][i].v, acc3, 0, 0, 0);
      }
    }
    par ^= 1;
    return reduce4(acc0, acc1, acc2, acc3);
  };

  auto block_sum = [&](float v) -> float {
#pragma unroll
    for (int o = 32; o; o >>= 1) v += __shfl_down(v, o, 64);
    __syncthreads();
    if (lane == 0) bred[w] = v;
    __syncthreads();
    return (tid == 0) ? (bred[0] + bred[1] + bred[2] + bred[3]) : 0.0f;
  };

  // single-level deterministic grid reduce (agent scope; data-as-flag,
  // batched polls — R10)
  auto grid_reduce = [&](float va, float vb, int sa, int sb, bool two) -> float2 {
    float ba = block_sum(va);
    float bb = two ? block_sum(vb) : 0.0f;
    if (tid == 0) {
      AST((unsigned*)&PART1[sa * 256 + blk], __float_as_uint(ba) | 1u);
      if (two) AST((unsigned*)&PART1[sb * 256 + blk], __float_as_uint(bb) | 1u);
    }
    if (w == 0) {
      const unsigned* pa = (const unsigned*)&PART1[sa * 256 + lane];
      const unsigned* pb = (const unsigned*)&PART1[sb * 256 + lane];
      unsigned ua0, ua1, ua2, ua3, ub0 = 1u, ub1 = 1u, ub2 = 1u, ub3 = 1u;
      while (true) {
        ua0 = ALD(pa);
        ua1 = ALD(pa + 64);
        ua2 = ALD(pa + 128);
        ua3 = ALD(pa + 192);
        if (two) {
          ub0 = ALD(pb);
          ub1 = ALD(pb + 64);
          ub2 = ALD(pb + 128);
          ub3 = ALD(pb + 192);
        }
        if ((ua0 & ua1 & ua2 & ua3 & ub0 & ub1 & ub2 & ub3) != 0u ||
            (ua0 && ua1 && ua2 && ua3 && ub0 && ub1 && ub2 && ub3)) break;
        __builtin_amdgcn_s_sleep(1);
      }
      float x0 = __uint_as_float(ua0) + __uint_as_float(ua1) +
                 __uint_as_float(ua2) + __uint_as_float(ua3);
      float x1 = 0.0f;
      if (two)
        x1 = __uint_as_float(ub0) + __uint_as_float(ub1) +
             __uint_as_float(ub2) + __uint_as_float(ub3);
#pragma unroll
      for (int o = 32; o; o >>= 1) {
        x0 += __shfl_down(x0, o, 64);
        x1 += __shfl_down(x1, o, 64);
      }
      if (lane == 0) { shb0s = x0; shb1s = x1; }
    }
    __syncthreads();
    return make_float2(shb0s, shb1s);
  };

  // ---- phase A0: y = (x @ P) patch, K=512 MFMA vs pre-packed P-frags
  // (ldsX already staged + synced above) ----
  floatx4 y, fy, k2, k3, k4, k5, k6, k7, yn, av;
  {
    floatx4 a0 = {0.f, 0.f, 0.f, 0.f}, a1 = a0, a2 = a0, a3 = a0;
#pragma unroll
    for (int i = 0; i < 4; ++i) {
      UB a, b;
      a.u = *(const uint4*)(ldsX + ((size_t)(4 * w + i) * 64 + lane) * 8);
      b.u = *(const uint4*)(BfP + (((size_t)(cb * 4 + 0) * 16 + 4 * w + i) * 64 + lane) * 8);
      a0 = __builtin_amdgcn_mfma_f32_16x16x32_bf16(a.v, b.v, a0, 0, 0, 0);
      b.u = *(const uint4*)(BfP + (((size_t)(cb * 4 + 1) * 16 + 4 * w + i) * 64 + lane) * 8);
      a1 = __builtin_amdgcn_mfma_f32_16x16x32_bf16(a.v, b.v, a1, 0, 0, 0);
      b.u = *(const uint4*)(BfP + (((size_t)(cb * 4 + 2) * 16 + 4 * w + i) * 64 + lane) * 8);
      a2 = __builtin_amdgcn_mfma_f32_16x16x32_bf16(a.v, b.v, a2, 0, 0, 0);
      b.u = *(const uint4*)(BfP + (((size_t)(cb * 4 + 3) * 16 + 4 * w + i) * 64 + lane) * 8);
      a3 = __builtin_amdgcn_mfma_f32_16x16x32_bf16(a.v, b.v, a3, 0, 0, 0);
    }
    y = reduce4(a0, a1, a2, a3);
  }

  // ---- initial step selection (scipy _select_initial_step) ----
  write_basis(y, TCc + TBc * 0.0f);
  rg_barrier();
  fy = gemm();  // f0
  {
    float s0 = 0.f, s1 = 0.f;
#pragma unroll
    for (int r = 0; r < 4; ++r) {
      float sv = ATOLc + RTOLc * fabsf(y[r]);
      float a = y[r] / sv, b = fy[r] / sv;
      s0 += a * a;
      s1 += b * b;
    }
    float2 d01 = grid_reduce(s0, s1, 0, 1, true);
    const float d0 = sqrtf(d01.x / NELF);
    const float d1 = sqrtf(d01.y / NELF);
    const float h0 = (d0 < 1e-5f || d1 < 1e-5f) ? 1e-6f : 0.01f * d0 / d1;
    av = y + h0 * fy;
    write_basis(av, TCc + TBc * h0);
    rg_barrier();
    k2 = gemm();  // f1 (temp)
    float s2 = 0.f;
#pragma unroll
    for (int r = 0; r < 4; ++r) {
      float sv = ATOLc + RTOLc * fabsf(y[r]);
      float dd = (k2[r] - fy[r]) / sv;
      s2 += dd * dd;
    }
    const float d2 = sqrtf(grid_reduce(s2, 0.f, 2, 0, false).x / NELF) / h0;
    const float dmax = fmaxf(d1, d2);
    const float h1i = (dmax <= 1e-15f) ? fmaxf(1e-6f, h0 * 1e-3f) : powf(0.01f / dmax, 0.2f);
    float h = fminf(fminf(100.0f * h0, h1i), 1.0f);
    float t = 0.0f;
    bool done = false;
    int it = 0;

    const float a21 = (float)(1.0 / 5.0);
    const float a31 = (float)(3.0 / 40.0), a32 = (float)(9.0 / 40.0);
    const float a41 = (float)(44.0 / 45.0), a42 = (float)(-56.0 / 15.0), a43 = (float)(32.0 / 9.0);
    const float a51 = (float)(19372.0 / 6561.0), a52 = (float)(-25360.0 / 2187.0),
                a53 = (float)(64448.0 / 6561.0), a54 = (float)(-212.0 / 729.0);
    const float a61 = (float)(9017.0 / 3168.0), a62 = (float)(-355.0 / 33.0),
                a63 = (float)(46732.0 / 5247.0), a64 = (float)(49.0 / 176.0),
                a65 = (float)(-5103.0 / 18656.0);
    const float b1 = (float)(35.0 / 384.0), b3 = (float)(500.0 / 1113.0),
                b4 = (float)(125.0 / 192.0), b5 = (float)(-2187.0 / 6784.0),
                b6 = (float)(11.0 / 84.0);
    const float e1c = (float)(71.0 / 57600.0), e3c = (float)(-71.0 / 16695.0),
                e4c = (float)(71.0 / 1920.0), e5c = (float)(-17253.0 / 339200.0),
                e6c = (float)(22.0 / 525.0), e7c = (float)(-1.0 / 40.0);
    const float c89 = (float)(8.0 / 9.0);

    while (true) {
      const float hs = fminf(h, 1.0f - t);

      av = y + (hs * a21) * fy;
      write_basis(av, TCc + TBc * (t + 0.2f * hs));
      rg_barrier();
      k2 = gemm();

      av = y + hs * (a31 * fy + a32 * k2);
      write_basis(av, TCc + TBc * (t + 0.3f * hs));
      rg_barrier();
      k3 = gemm();

      av = y + hs * (a41 * fy + a42 * k2 + a43 * k3);
      write_basis(av, TCc + TBc * (t + 0.8f * hs));
      rg_barrier();
      k4 = gemm();

      av = y + hs * (a51 * fy + a52 * k2 + a53 * k3 + a54 * k4);
      write_basis(av, TCc + TBc * (t + c89 * hs));
      rg_barrier();
      k5 = gemm();

      av = y + hs * (a61 * fy + a62 * k2 + a63 * k3 + a64 * k4 + a65 * k5);
      write_basis(av, TCc + TBc * (t + hs));
      rg_barrier();
      k6 = gemm();

      yn = y + hs * (b1 * fy + b3 * k3 + b4 * k4 + b5 * k5 + b6 * k6);
      write_basis(yn, TCc + TBc * (t + hs));  // FSAL stage input
      rg_barrier();
      k7 = gemm();

      float es = 0.f;
#pragma unroll
      for (int r = 0; r < 4; ++r) {
        float errc = hs * (e1c * fy[r] + e3c * k3[r] + e4c * k4[r] + e5c * k5[r] +
                           e6c * k6[r] + e7c * k7[r]);
        float sv = ATOLc + RTOLc * fmaxf(fabsf(y[r]), fabsf(yn[r]));
        float dd = errc / sv;
        es += dd * dd;
      }
      const float en = sqrtf(grid_reduce(es, 0.f, 3 + it, 0, false).x / NELF);
      const bool accept = en < 1.0f;
      const float safe = fmaxf(en, 1e-10f);
      float fac = 0.9f * powf(safe, -0.2f);
      fac = accept ? fminf(10.0f, fac) : fmaxf(0.2f, fac);
      if (accept) {
        t = t + hs;
        y = yn;
        fy = k7;
      }
      h = hs * fac;
      done = done || (t >= 1.0f - 1e-7f);
      ++it;
      if (done || it >= 20) break;
    }
  }

  // ---- final phase: out = A_f @ F. Exchange y as K=512 frags in the AF0
  // region (safe: last grid_reduce was a full grid sync; no more basis gemms).
  {
    uint32_t d0 = f2bf(y[0]) | (f2bf(y[1]) << 16);
    uint32_t d1 = f2bf(y[2]) | (f2bf(y[3]) << 16);
    const int kcF = gcq >> 3;
    const int alF = rl | (((gcq >> 1) & 3) << 4);
    unsigned long long* p = YF + ((size_t)(rg * 16 + kcF) * 64 + alF) * 2 + (gcq & 1);
    unsigned long long v = (unsigned long long)d0 | ((unsigned long long)d1 << 32);
    if (fastp) {
      *(volatile unsigned long long*)p = v;
    } else {
      AST(p, v);
    }
  }
  rg_barrier();
  {
    floatx4 a0 = {0.f, 0.f, 0.f, 0.f}, a1 = a0, a2 = a0, a3 = a0;
#pragma unroll
    for (int i = 0; i < 4; ++i) {
      UB2 a;
      const size_t base = ((size_t)(rg * 16 + 4 * w + i) * 64 + lane) * 2;
      if (fastp) {
        a.x = ld128_x(YF + base);
      } else {
        a.q[0] = ALD(YF + base);
        a.q[1] = ALD(YF + base + 1);
      }
      UB b;
      b.u = *(const uint4*)(BfF + (((size_t)(cb * 4 + 0) * 16 + 4 * w + i) * 64 + lane) * 8);
      a0 = __builtin_amdgcn_mfma_f32_16x16x32_bf16(a.v, b.v, a0, 0, 0, 0);
      b.u = *(const uint4*)(BfF + (((size_t)(cb * 4 + 1) * 16 + 4 * w + i) * 64 + lane) * 8);
      a1 = __builtin_amdgcn_mfma_f32_16x16x32_bf16(a.v, b.v, a1, 0, 0, 0);
      b.u = *(const uint4*)(BfF + (((size_t)(cb * 4 + 2) * 16 + 4 * w + i) * 64 + lane) * 8);
      a2 = __builtin_amdgcn_mfma_f32_16x16x32_bf16(a.v, b.v, a2, 0, 0, 0);
      b.u = *(const uint4*)(BfF + (((size_t)(cb * 4 + 3) * 16 + 4 * w + i) * 64 + lane) * 8);
      a3 = __builtin_amdgcn_mfma_f32_16x16x32_bf16(a.v, b.v, a3, 0, 0, 0);
    }
    floatx4 o = reduce4(a0, a1, a2, a3);
    *(floatx4*)(out + (size_t)(rg * 16 + rl) * NDT + cb * 64 + (tid >> 4) * 4) = o;
  }
}

extern "C" void kernel_launch(void* const* d_in, const int* in_sizes, int n_in,
                              void* d_out, int out_size, void* d_ws, size_t ws_size,
                              hipStream_t stream) {
  (void)in_sizes; (void)n_in; (void)out_size; (void)ws_size;
  const float* x = (const float*)d_in[0];
  const float* P = (const float*)d_in[1];
  const float* C = (const float*)d_in[2];
  const float* F = (const float*)d_in[3];
  float* out = (float*)d_out;
  float* ws = (float*)d_ws;

  // zero ctl region (FLAG + reserved + PART1): 10240 uints. Capture-safe
  // (memset nodes are what the harness's own reset uses).
  hipMemsetAsync(ws, 0, 10240 * sizeof(unsigned), stream);
  // single fused kernel: pack + A0 + RK45 + out
  hipLaunchKernelGGL(ode_fused, dim3(256), dim3(256), 0, stream, x, C, P, F, out, ws);
}